// Round 3
// baseline (286.282 us; speedup 1.0000x reference)
//
#include <hip/hip_runtime.h>
#include <stdint.h>

#define NVOX 40000
#define CCH  128
#define K2   9
#define NH   5
#define TILES 313

typedef __attribute__((ext_vector_type(8))) short bf16x8;
typedef __attribute__((ext_vector_type(4))) float f32x4;

__device__ __forceinline__ unsigned short f2b(float f) {
  union { float f; unsigned int u; } v; v.f = f;
  return (unsigned short)((v.u + 0x7fffu + ((v.u >> 16) & 1u)) >> 16);
}
__device__ __forceinline__ float b2f(unsigned short u) {
  union { unsigned int u; float f; } v; v.u = ((unsigned int)u) << 16;
  return v.f;
}
__device__ __forceinline__ void g2l16(const void* g, void* l) {
  __builtin_amdgcn_global_load_lds(
      (const __attribute__((address_space(1))) unsigned int*)g,
      (__attribute__((address_space(3))) unsigned int*)l, 16, 0, 0);
}
// XOR-swizzled LDS address (shorts) for logical (row, short-col)
__device__ __forceinline__ int swz(int row, int col) {
  return row * 128 + ((((col >> 3) ^ (row & 15)) << 3) | (col & 7));
}

// ---- fused prep: feats fp32->bf16 (blocks 0..4999), W1 cvt+transpose (5000..5179) ----
__global__ void prep(const float4* __restrict__ feats, ushort4* __restrict__ fb,
                     const float* __restrict__ w1, unsigned short* __restrict__ w1t) {
  __shared__ unsigned short t[128 * 34];
  int b = blockIdx.x;
  if (b < 5000) {
    int i = b * 256 + threadIdx.x;
    if (i < NVOX * CCH / 4) {
      float4 v = feats[i];
      ushort4 r;
      r.x = f2b(v.x); r.y = f2b(v.y); r.z = f2b(v.z); r.w = f2b(v.w);
      fb[i] = r;
    }
    return;
  }
  int bb = b - 5000;           // 0..179
  int tile = bb >> 2;          // h*9+k, 0..44
  int q = bb & 3;              // c-quarter
  const float* src = w1 + (size_t)tile * 16384 + q * 32 * 128;
  for (int e = threadIdx.x; e < 4096; e += 256) {
    int c = e >> 7, d = e & 127;
    t[d * 34 + c] = f2b(src[e]);
  }
  __syncthreads();
  unsigned short* dst = w1t + (size_t)tile * 16384 + q * 32;
  for (int e = threadIdx.x; e < 4096; e += 256) {
    int d = e >> 5, c = e & 31;
    dst[d * 128 + c] = t[d * 34 + c];
  }
}

// ---- gather + GEMM: A via swizzled LDS, B direct to registers (L2-hot) ----
// grid: 1600 blocks; supergroup of 40 = 8 XCD-lanes x 5 heads, so the 5 heads
// of one row-tile land on the same XCD temporally close (gather L2 reuse x5).
__global__ void __launch_bounds__(256, 3) conv_gemm(
    const unsigned short* __restrict__ fb,   // feats bf16 [N][128]
    const int* __restrict__ nbr,             // [N][9]
    const unsigned short* __restrict__ w1t,  // [H][9][d=128][c=128] bf16
    unsigned short* __restrict__ yb,         // [H][N][128] bf16
    float* __restrict__ sums)                // [2][H][128]
{
  __shared__ unsigned short As[128 * 128];
  __shared__ int idxs[128 * K2];

  const int bid = blockIdx.x;
  const int s = bid / 40;
  const int r = bid % 40;
  const int h = r >> 3;        // 0..4
  const int x = r & 7;         // xcd lane
  const int tile = s * 8 + x;
  if (tile >= TILES) return;
  const int n0 = tile * 128;

  const int tid = threadIdx.x;
  const int wave = tid >> 6;
  const int lane = tid & 63;
  const int lrow = lane >> 4;  // 0..3
  const int lcol = lane & 15;  // 0..15
  const int wm = wave >> 1, wn = wave & 1;

  for (int i = tid; i < 128 * K2; i += 256) {
    int rr = i / K2;
    int kk = i - rr * K2;
    int gn = n0 + rr; if (gn > NVOX - 1) gn = NVOX - 1;
    idxs[i] = nbr[gn * K2 + kk];
  }
  __syncthreads();

  f32x4 acc[4][4] = {};

  // stage A(0)
  {
    int ridx[8];
#pragma unroll
    for (int i = 0; i < 8; ++i)
      ridx[i] = idxs[(wave * 32 + i * 4 + lrow) * K2 + 0];
#pragma unroll
    for (int i = 0; i < 8; ++i) {
      int row = wave * 32 + i * 4 + lrow;
      g2l16(fb + (size_t)ridx[i] * CCH + ((lcol ^ (row & 15)) << 3),
            &As[(wave * 32 + i * 4) * CCH]);
    }
  }

  for (int k = 0; k < K2; ++k) {
    const unsigned short* wp = w1t + (((size_t)h * K2 + k) << 14);
    __syncthreads();  // A(k) staged (vmcnt drained by compiler)

#pragma unroll
    for (int kc = 0; kc < 4; ++kc) {
      bf16x8 af[4], bfr[4];
#pragma unroll
      for (int ni = 0; ni < 4; ++ni) {
        int row = wn * 64 + ni * 16 + lcol;
        bfr[ni] = *(const bf16x8*)(wp + row * CCH + kc * 32 + lrow * 8);
      }
#pragma unroll
      for (int mi = 0; mi < 4; ++mi) {
        int row = wm * 64 + mi * 16 + lcol;
        af[mi] = *(const bf16x8*)&As[row * CCH + (((kc * 4 + lrow) ^ (row & 15)) << 3)];
      }
#pragma unroll
      for (int mi = 0; mi < 4; ++mi)
#pragma unroll
        for (int ni = 0; ni < 4; ++ni)
          acc[mi][ni] = __builtin_amdgcn_mfma_f32_16x16x32_bf16(af[mi], bfr[ni], acc[mi][ni], 0, 0, 0);
    }
    __syncthreads();  // A consumed

    if (k + 1 < K2) {
      int ridx[8];
#pragma unroll
      for (int i = 0; i < 8; ++i)
        ridx[i] = idxs[(wave * 32 + i * 4 + lrow) * K2 + k + 1];
#pragma unroll
      for (int i = 0; i < 8; ++i) {
        int row = wave * 32 + i * 4 + lrow;
        g2l16(fb + (size_t)ridx[i] * CCH + ((lcol ^ (row & 15)) << 3),
              &As[(wave * 32 + i * 4) * CCH]);
      }
    }
  }

  // epilogue: acc -> LDS bf16, swizzled (C/D: col=lane&15, row=(lane>>4)*4+reg)
#pragma unroll
  for (int mi = 0; mi < 4; ++mi)
#pragma unroll
    for (int ni = 0; ni < 4; ++ni)
#pragma unroll
      for (int rr = 0; rr < 4; ++rr) {
        int row = wm * 64 + mi * 16 + lrow * 4 + rr;
        int col = wn * 64 + ni * 16 + lcol;
        As[swz(row, col)] = f2b(acc[mi][ni][rr]);
      }
  __syncthreads();

  // coalesced y store (un-swizzle on read)
  for (int i = tid; i < 2048; i += 256) {
    int row = i >> 4;
    int c = i & 15;
    if (n0 + row < NVOX)
      *(bf16x8*)(yb + ((size_t)h * NVOX + n0 + row) * CCH + c * 8) =
          *(const bf16x8*)&As[row * 128 + ((c ^ (row & 15)) << 3)];
  }

  // BN partial stats
  {
    int col = tid & 127, half = tid >> 7;
    int rbase = half * 64;
    int nvalid = NVOX - n0 - rbase;
    if (nvalid > 64) nvalid = 64;
    float sm = 0.f, q = 0.f;
    for (int rr = 0; rr < nvalid; ++rr) {
      float z = b2f(As[swz(rbase + rr, col)]);
      sm += z; q += z * z;
    }
    if (nvalid > 0) {
      atomicAdd(&sums[h * CCH + col], sm);
      atomicAdd(&sums[NH * CCH + h * CCH + col], q);
    }
  }
}

// ---- finalize BN ----
__global__ void finalize_bn(const float* __restrict__ sums, const float* __restrict__ gamma,
                            const float* __restrict__ beta, float* __restrict__ ssb) {
  int h = blockIdx.x, c = threadIdx.x;
  float mean = sums[h * CCH + c] * (1.f / NVOX);
  float var = sums[NH * CCH + h * CCH + c] * (1.f / NVOX) - mean * mean;
  float rstd = rsqrtf(var + 1e-5f);
  float scale = rstd * gamma[h * CCH + c];
  ssb[h * CCH + c] = scale;
  ssb[NH * CCH + h * CCH + c] = beta[h * CCH + c] - mean * scale;
}

// ---- BN + ReLU + 1x1 head, one thread per (head, voxel) ----
__global__ void __launch_bounds__(256) head_fuse(
    const unsigned short* __restrict__ yb, const float* __restrict__ ssb,
    const float* __restrict__ w_hm, const float* __restrict__ b_hm,
    const float* __restrict__ w_ce, const float* __restrict__ b_ce,
    const float* __restrict__ w_cz, const float* __restrict__ b_cz,
    const float* __restrict__ w_dm, const float* __restrict__ b_dm,
    const float* __restrict__ w_rt, const float* __restrict__ b_rt,
    float* __restrict__ out)
{
  int t = blockIdx.x * 256 + threadIdx.x;
  if (t >= NH * NVOX) return;
  int h = t / NVOX;          // wave-uniform except at boundaries
  int v = t - h * NVOX;

  const float* wp; const float* bp; int oc, off;
  switch (h) {
    case 0: wp = w_hm; bp = b_hm; oc = 3; off = 0; break;
    case 1: wp = w_ce; bp = b_ce; oc = 2; off = 3; break;
    case 2: wp = w_cz; bp = b_cz; oc = 1; off = 5; break;
    case 3: wp = w_dm; bp = b_dm; oc = 3; off = 6; break;
    default: wp = w_rt; bp = b_rt; oc = 2; off = 9; break;
  }
  float a0 = bp[0];
  float a1 = (oc > 1) ? bp[1] : 0.f;
  float a2 = (oc > 2) ? bp[2] : 0.f;

  const bf16x8* yp = (const bf16x8*)(yb + ((size_t)h * NVOX + v) * CCH);
  const float* sc = ssb + h * CCH;
  const float* sh = ssb + NH * CCH + h * CCH;

  for (int q8 = 0; q8 < 16; ++q8) {
    bf16x8 pk = yp[q8];
#pragma unroll
    for (int e = 0; e < 8; ++e) {
      int d = q8 * 8 + e;
      float z = fmaf(b2f((unsigned short)pk[e]), sc[d], sh[d]);
      z = fmaxf(z, 0.f);
      const float* wr = wp + d * oc;
      a0 = fmaf(z, wr[0], a0);
      if (oc > 1) a1 = fmaf(z, wr[1], a1);
      if (oc > 2) a2 = fmaf(z, wr[2], a2);
    }
  }
  float* op = out + (size_t)v * 11 + off;
  op[0] = a0;
  if (oc > 1) op[1] = a1;
  if (oc > 2) op[2] = a2;
}

extern "C" void kernel_launch(void* const* d_in, const int* in_sizes, int n_in,
                              void* d_out, int out_size, void* d_ws, size_t ws_size,
                              hipStream_t stream) {
  const float* feats = (const float*)d_in[0];
  const int*   nbr   = (const int*)d_in[1];
  const float* W1    = (const float*)d_in[2];
  const float* gamma = (const float*)d_in[3];
  const float* beta  = (const float*)d_in[4];
  const float* w_hm = (const float*)d_in[5];  const float* b_hm = (const float*)d_in[6];
  const float* w_ce = (const float*)d_in[7];  const float* b_ce = (const float*)d_in[8];
  const float* w_cz = (const float*)d_in[9];  const float* b_cz = (const float*)d_in[10];
  const float* w_dm = (const float*)d_in[11]; const float* b_dm = (const float*)d_in[12];
  const float* w_rt = (const float*)d_in[13]; const float* b_rt = (const float*)d_in[14];
  float* out = (float*)d_out;

  char* ws = (char*)d_ws;
  unsigned short* w1t = (unsigned short*)ws;                   // 11,796,480 B
  unsigned short* fb  = (unsigned short*)(ws + 11796480);      // 10,240,000 B
  unsigned short* yb  = (unsigned short*)(ws + 22036480);      // 51,200,000 B
  float* sums = (float*)(ws + 73236480);                       // 5,120 B
  float* ssb  = (float*)(ws + 73241600);                       // 5,120 B

  hipMemsetAsync(sums, 0, 2 * NH * CCH * sizeof(float), stream);
  prep<<<5180, 256, 0, stream>>>((const float4*)feats, (ushort4*)fb, W1, w1t);
  conv_gemm<<<1600, 256, 0, stream>>>(fb, nbr, w1t, yb, sums);
  finalize_bn<<<NH, CCH, 0, stream>>>(sums, gamma, beta, ssb);
  head_fuse<<<782, 256, 0, stream>>>(yb, ssb, w_hm, b_hm, w_ce, b_ce, w_cz, b_cz,
                                     w_dm, b_dm, w_rt, b_rt, out);
}